// Round 1
// 766.901 us; speedup vs baseline: 1.0360x; 1.0360x over previous
//
#include <hip/hip_runtime.h>
#include <hip/hip_bf16.h>

// Problem constants (fixed by reference): B=64, C=32, V=1024, L=12, ORDER=2
// Decomposition:
//   adp = softmax(relu(nv1@nv2), axis=1)
//   Bt_cat[6][1024][1024] bf16:  slice k, row w, col v = G_k[v][w]
//     G = {A1, A1^2, A2, A2^2, adp, adp^2}
//   xT bf16 rows m=(b*12+l)*32+c, cols v   (row-major K=1024)
//   R[m,(k,w)] = sum_v xT[m,v]*G_k[v,w]  stored in layout [b][l][k][c][w] bf16
//   out[b,o,w,l] = bias[o] + sum_c W[o,c]*x[b,c,w,l] + sum_{k,c} W[o,32(k+1)+c]*R_k[b,c,w,l]
//
// R2 change: main diffusion GEMM ported from the 128^2 2-barrier structure
// (~910 TF, the m97 ceiling) to a 256^2 8-wave K-half-phased schedule with
// counted vmcnt (never 0 in steady state) + s_setprio around MFMA clusters.
// 4-unit LDS ring (32 KB/unit, 128 KiB total), staged 3 K-halves ahead.

typedef __attribute__((ext_vector_type(8))) short short8;
typedef __attribute__((ext_vector_type(4))) float floatx4;

#define V_DIM 1024
#define L_DIM 12
#define B_DIM 64
#define C_DIM 32

// ---------------- adp: relu + row softmax --------------------------------
__global__ __launch_bounds__(128) void adp_kernel(
    const float* __restrict__ nv1, const float* __restrict__ nv2,
    float* __restrict__ adp) {
  const int v = blockIdx.x, tid = threadIdx.x;
  float n1[10];
#pragma unroll
  for (int i = 0; i < 10; ++i) n1[i] = nv1[v * 10 + i];
  __shared__ float red[128];
  float e[8];
  float lmax = -1e30f;
#pragma unroll
  for (int j = 0; j < 8; ++j) {
    int w = tid + j * 128;
    float s = 0.f;
#pragma unroll
    for (int i = 0; i < 10; ++i) s += n1[i] * nv2[i * V_DIM + w];
    s = fmaxf(s, 0.f);
    e[j] = s;
    lmax = fmaxf(lmax, s);
  }
  red[tid] = lmax; __syncthreads();
  for (int s = 64; s > 0; s >>= 1) {
    if (tid < s) red[tid] = fmaxf(red[tid], red[tid + s]);
    __syncthreads();
  }
  float mx = red[0]; __syncthreads();
  float lsum = 0.f;
#pragma unroll
  for (int j = 0; j < 8; ++j) { e[j] = __expf(e[j] - mx); lsum += e[j]; }
  red[tid] = lsum; __syncthreads();
  for (int s = 64; s > 0; s >>= 1) {
    if (tid < s) red[tid] += red[tid + s];
    __syncthreads();
  }
  float inv = 1.f / red[0];
#pragma unroll
  for (int j = 0; j < 8; ++j) adp[(size_t)v * V_DIM + tid + j * 128] = e[j] * inv;
}

// ------------- cast supports to bf16: straight + transposed ---------------
__global__ __launch_bounds__(256) void cast_transpose(
    const float* __restrict__ A1, const float* __restrict__ A2,
    const float* __restrict__ adp, __hip_bfloat16* __restrict__ As,
    __hip_bfloat16* __restrict__ BtCat) {
  const int z = blockIdx.z;
  const float* src = (z == 0) ? A1 : (z == 1) ? A2 : adp;
  __hip_bfloat16* sdst = As + (size_t)z * V_DIM * V_DIM;
  __hip_bfloat16* tdst = BtCat + (size_t)(2 * z) * V_DIM * V_DIM;
  __shared__ float tile[64][65];
  const int v0 = blockIdx.y * 64, w0 = blockIdx.x * 64;
  const int tc = threadIdx.x & 15, tr = threadIdx.x >> 4;
#pragma unroll
  for (int i = 0; i < 4; ++i) {
    int r = tr + i * 16;
    float4 val = *(const float4*)(src + (size_t)(v0 + r) * V_DIM + w0 + tc * 4);
    tile[r][tc * 4 + 0] = val.x; tile[r][tc * 4 + 1] = val.y;
    tile[r][tc * 4 + 2] = val.z; tile[r][tc * 4 + 3] = val.w;
    __hip_bfloat16* sp = sdst + (size_t)(v0 + r) * V_DIM + w0 + tc * 4;
    sp[0] = __float2bfloat16(val.x); sp[1] = __float2bfloat16(val.y);
    sp[2] = __float2bfloat16(val.z); sp[3] = __float2bfloat16(val.w);
  }
  __syncthreads();
#pragma unroll
  for (int i = 0; i < 4; ++i) {
    int r = tr + i * 16;  // output row = w0 + r
    __hip_bfloat16* tp = tdst + (size_t)(w0 + r) * V_DIM + v0 + tc * 4;
#pragma unroll
    for (int j = 0; j < 4; ++j) tp[j] = __float2bfloat16(tile[tc * 4 + j][r]);
  }
}

// ------------- x [B,C,V,L] fp32 -> xT bf16 rows (b*12+l)*32+c -------------
__global__ __launch_bounds__(256) void transpose_x_k(
    const float* __restrict__ x, __hip_bfloat16* __restrict__ xT) {
  const int bc = blockIdx.x;         // b*32+c
  const int b = bc >> 5, c = bc & 31;
  __shared__ __align__(16) __hip_bfloat16 tile[V_DIM * L_DIM];  // idx v*12+l
  const float4* src = (const float4*)(x + (size_t)bc * (V_DIM * L_DIM));
#pragma unroll
  for (int i = 0; i < 12; ++i) {
    int idx = threadIdx.x + i * 256;  // 3072 float4
    float4 v = src[idx];
    int e = idx * 4;
    tile[e + 0] = __float2bfloat16(v.x); tile[e + 1] = __float2bfloat16(v.y);
    tile[e + 2] = __float2bfloat16(v.z); tile[e + 3] = __float2bfloat16(v.w);
  }
  __syncthreads();
  for (int l = 0; l < L_DIM; ++l) {
    __hip_bfloat16* dst = xT + ((size_t)(b * L_DIM + l) * C_DIM + c) * V_DIM;
    for (int v = threadIdx.x; v < V_DIM; v += 256) dst[v] = tile[v * L_DIM + l];
  }
}

// ---------------- async global->LDS helper --------------------------------
__device__ __forceinline__ void gll16(const __hip_bfloat16* g, __hip_bfloat16* l) {
  __builtin_amdgcn_global_load_lds(
      (const __attribute__((address_space(1))) void*)g,
      (__attribute__((address_space(3))) void*)l, 16, 0, 0);
}

// ---------------- MFMA GEMM (128^2, 2-barrier): squares only --------------
// A [M,K] bf16 row-major, Bt [N,K] bf16 row-major, C row-major bf16 [M,N].
template <int MODE>
__global__ __launch_bounds__(256) void gemm_bt(
    const __hip_bfloat16* __restrict__ Abase,
    const __hip_bfloat16* __restrict__ Btbase,
    __hip_bfloat16* __restrict__ Cbase, int M, int N, int K,
    long long aStride, long long bStride, long long cStride) {
  const __hip_bfloat16* A = Abase + (size_t)blockIdx.z * aStride;
  const __hip_bfloat16* Bt = Btbase + (size_t)blockIdx.z * bStride;
  __hip_bfloat16* C = Cbase + (size_t)blockIdx.z * cStride;
  __shared__ __align__(16) __hip_bfloat16 lA[128 * 64];
  __shared__ __align__(16) __hip_bfloat16 lB[128 * 64];
  const int tid = threadIdx.x;
  const int wv = tid >> 6, lane = tid & 63;
  const int wm = wv >> 1, wn = wv & 1;
  const int m0 = blockIdx.y * 128, n0 = blockIdx.x * 128;
  const int lrow = lane >> 3, lcol = lane & 7;  // staging: 8 rows / wave-instr
  const int gcol = lcol ^ (lrow & 7);           // XOR bank swizzle
  const int fr = lane & 15, quad = lane >> 4;   // fragment coords
  const int sw = fr & 7;                        // read-side swizzle key

  floatx4 acc[4][4];
#pragma unroll
  for (int i = 0; i < 4; ++i)
#pragma unroll
    for (int j = 0; j < 4; ++j) acc[i][j] = (floatx4){0.f, 0.f, 0.f, 0.f};

  for (int kt = 0; kt < K; kt += 64) {
    __syncthreads();  // previous tile fully consumed
#pragma unroll
    for (int i = 0; i < 4; ++i) {
      int r0 = (wv * 4 + i) * 8;
      gll16(A + (size_t)(m0 + r0 + lrow) * K + kt + gcol * 8, &lA[r0 * 64]);
      gll16(Bt + (size_t)(n0 + r0 + lrow) * K + kt + gcol * 8, &lB[r0 * 64]);
    }
    __syncthreads();  // drains vmcnt(0): staged data visible
#pragma unroll
    for (int ks = 0; ks < 2; ++ks) {
      const int chunk = (ks * 4 + quad) ^ sw;   // swizzled K-chunk slot
      short8 af[4], bfr[4];
#pragma unroll
      for (int t = 0; t < 4; ++t) {
        af[t] = *(const short8*)&lA[(wm * 64 + t * 16 + fr) * 64 + chunk * 8];
        bfr[t] = *(const short8*)&lB[(wn * 64 + t * 16 + fr) * 64 + chunk * 8];
      }
#pragma unroll
      for (int i = 0; i < 4; ++i)
#pragma unroll
        for (int j = 0; j < 4; ++j)
          acc[i][j] = __builtin_amdgcn_mfma_f32_16x16x32_bf16(af[i], bfr[j], acc[i][j], 0, 0, 0);
    }
  }
  // epilogue: C/D layout col=lane&15, row=quad*4+reg (m89-verified)
#pragma unroll
  for (int i = 0; i < 4; ++i) {
#pragma unroll
    for (int j = 0; j < 4; ++j) {
      int mb = m0 + wm * 64 + i * 16 + quad * 4;
      int n = n0 + wn * 64 + j * 16 + fr;
#pragma unroll
      for (int r = 0; r < 4; ++r) {
        int m = mb + r;
        float val = acc[i][j][r];
        size_t idx;
        if (MODE == 0) {
          idx = (size_t)m * N + n;
        } else {
          int c = m & 31, bl = m >> 5, k = n >> 10, w = n & 1023;
          idx = (((size_t)bl * 6 + k) * 32 + c) * 1024 + w;
        }
        C[idx] = __float2bfloat16(val);
      }
    }
  }
}

// ------------- main diffusion GEMM: 256^2, 8-wave, phased pipeline --------
// A = xT [24576][1024], Bt = BtCat [6144][1024]; C = R scatter layout.
// K processed in 32-wide halves; 4-unit LDS ring (unit = A 256x32 + B 256x32
// bf16 = 32 KB). Staging runs 3 halves ahead: iter h issues half h+3's loads
// into unit (h+3)&3 = (h-1)&3 (whose readers finished at iter h-1's closing
// barrier).  Counted vmcnt(8) at end of iter h retires half h+1's 4 loads
// (outstanding afterward: halves h+2,h+3 = 8) -- never a vmcnt(0) drain
// until the 2-half tail.
// Per phase: {ds_read 4-8 x b128 | issue 2 gll16 -> s_barrier ->
//             setprio(1) -> 16 MFMA -> setprio(0) -> s_barrier}.
// LDS chunk swizzle: slot = chunk ^ ((row>>1)&3); with 64-B rows this puts
// a b128 fragment-read at exactly 8 words/bank (conflict-free) while the
// gll16 linear lane->slot map is matched by pre-swizzling the global column.
__global__ __launch_bounds__(512, 2) void gemm256(
    const __hip_bfloat16* __restrict__ A,
    const __hip_bfloat16* __restrict__ Bt,
    __hip_bfloat16* __restrict__ C) {
  constexpr int K = 1024;
  constexpr int NH = K / 32;  // 32 K-halves
  __shared__ __align__(16) __hip_bfloat16 sA[4][8192];  // [unit][row*32+col]
  __shared__ __align__(16) __hip_bfloat16 sB[4][8192];
  const int tid = threadIdx.x;
  const int wv = tid >> 6, lane = tid & 63;
  const int wm = wv >> 2, wn = wv & 3;          // 2x4 wave grid, 128x64 C/wave
  const int fr = lane & 15, quad = lane >> 4;
  const int rslot = (quad ^ ((fr >> 1) & 3)) << 3;   // swizzled 8-elem slot
  const int aoff = (wm * 128 + fr) * 32 + rslot;     // A-frag elem offset
  const int boff = (wn * 64 + fr) * 32 + rslot;      // B-frag elem offset
  const int m0 = blockIdx.y * 256, n0 = blockIdx.x * 256;
  // staging: per K-half each thread issues A x2 then B x2 (16 rows / instr)
  const int srow = wv * 32 + (lane >> 2);            // local row; inst1 = +16
  const int gch = ((lane & 3) ^ ((lane >> 3) & 3)) << 3;  // pre-swizzled col
  const __hip_bfloat16* Ag = A + (size_t)(m0 + srow) * K + gch;
  const __hip_bfloat16* Bg = Bt + (size_t)(n0 + srow) * K + gch;
  const int sbase = (wv * 32) * 32;                  // LDS elem base; +512 = inst1

  floatx4 acc[8][4];
#pragma unroll
  for (int i = 0; i < 8; ++i)
#pragma unroll
    for (int j = 0; j < 4; ++j) acc[i][j] = (floatx4){0.f, 0.f, 0.f, 0.f};

  // prologue: stage halves 0..2 (issue order per half: A0,A1,B0,B1 -- must
  // match steady-state order for the vmcnt accounting)
#pragma unroll
  for (int hp = 0; hp < 3; ++hp) {
    gll16(Ag + hp * 32, &sA[hp][sbase]);
    gll16(Ag + (size_t)16 * K + hp * 32, &sA[hp][sbase + 512]);
    gll16(Bg + hp * 32, &sB[hp][sbase]);
    gll16(Bg + (size_t)16 * K + hp * 32, &sB[hp][sbase + 512]);
  }
  asm volatile("s_waitcnt vmcnt(8)" ::: "memory");   // half 0 resident
  __builtin_amdgcn_s_barrier();

  for (int h = 0; h < NH; ++h) {
    const int u = h & 3;
    short8 af[4], bf[4];
    // ---- phase 0: M-half 0 (acc rows 0..3), all 4 B-frags ----
#pragma unroll
    for (int j = 0; j < 4; ++j) bf[j] = *(const short8*)&sB[u][boff + j * 512];
#pragma unroll
    for (int i = 0; i < 4; ++i) af[i] = *(const short8*)&sA[u][aoff + i * 512];
    if (h + 3 < NH) {
      const int h3 = h + 3, u3 = h3 & 3;
      gll16(Ag + h3 * 32, &sA[u3][sbase]);
      gll16(Ag + (size_t)16 * K + h3 * 32, &sA[u3][sbase + 512]);
    }
    __builtin_amdgcn_s_barrier();
    __builtin_amdgcn_s_setprio(1);
#pragma unroll
    for (int i = 0; i < 4; ++i)
#pragma unroll
      for (int j = 0; j < 4; ++j)
        acc[i][j] = __builtin_amdgcn_mfma_f32_16x16x32_bf16(af[i], bf[j], acc[i][j], 0, 0, 0);
    __builtin_amdgcn_s_setprio(0);
    __builtin_amdgcn_s_barrier();
    // ---- phase 1: M-half 1 (acc rows 4..7), B-frags held ----
#pragma unroll
    for (int i = 0; i < 4; ++i) af[i] = *(const short8*)&sA[u][aoff + (4 + i) * 512];
    if (h + 3 < NH) {
      const int h3 = h + 3, u3 = h3 & 3;
      gll16(Bg + h3 * 32, &sB[u3][sbase]);
      gll16(Bg + (size_t)16 * K + h3 * 32, &sB[u3][sbase + 512]);
    }
    __builtin_amdgcn_s_barrier();
    __builtin_amdgcn_s_setprio(1);
#pragma unroll
    for (int i = 0; i < 4; ++i)
#pragma unroll
      for (int j = 0; j < 4; ++j)
        acc[4 + i][j] = __builtin_amdgcn_mfma_f32_16x16x32_bf16(af[i], bf[j], acc[4 + i][j], 0, 0, 0);
    __builtin_amdgcn_s_setprio(0);
    // counted wait: retire half h+1 (next iter's unit) before its readers
    if (h < NH - 3) {
      asm volatile("s_waitcnt vmcnt(8)" ::: "memory");
    } else if (h == NH - 3) {
      asm volatile("s_waitcnt vmcnt(4)" ::: "memory");
    } else if (h == NH - 2) {
      asm volatile("s_waitcnt vmcnt(0)" ::: "memory");
    }
    __builtin_amdgcn_s_barrier();
  }

  // epilogue: R-layout scatter (same mapping as gemm_bt<1>)
#pragma unroll
  for (int i = 0; i < 8; ++i) {
#pragma unroll
    for (int j = 0; j < 4; ++j) {
      int mb = m0 + wm * 128 + i * 16 + quad * 4;
      int n = n0 + wn * 64 + j * 16 + fr;
      int k = n >> 10, w = n & 1023;
#pragma unroll
      for (int r = 0; r < 4; ++r) {
        int m = mb + r;
        int c = m & 31, bl = m >> 5;
        size_t idx = (((size_t)bl * 6 + k) * 32 + c) * 1024 + w;
        C[idx] = __float2bfloat16(acc[i][j][r]);
      }
    }
  }
}

// ---------------- mix: out = W * concat(x, hops) + b ----------------------
__global__ __launch_bounds__(256) void mix_kernel(
    const __hip_bfloat16* __restrict__ R, const __hip_bfloat16* __restrict__ xT,
    const float* __restrict__ W, const float* __restrict__ bias,
    float* __restrict__ out) {
  const int b = blockIdx.y, wt = blockIdx.x;
  const int tid = threadIdx.x;
  __shared__ __align__(16) __hip_bfloat16 tile[L_DIM * C_DIM * 64];  // [l][c][w64]
  __shared__ float Wl[7 * 32 * 32];  // Wl[(p*32+c)*32+o] = W[o][p*32+c]
  for (int i = tid; i < 7168; i += 256) {
    int o = i / 224, cc = i - o * 224;
    Wl[cc * 32 + o] = W[i];
  }
  float acc[3][32];
#pragma unroll
  for (int pt = 0; pt < 3; ++pt)
#pragma unroll
    for (int o = 0; o < 32; ++o) acc[pt][o] = bias[o];
  int wloc[3], ll[3];
#pragma unroll
  for (int pt = 0; pt < 3; ++pt) {
    int wl = tid + pt * 256;
    wloc[pt] = wl / 12;
    ll[pt] = wl - wloc[pt] * 12;
  }
  const int w0 = wt * 64;
  for (int k = 0; k < 7; ++k) {
    __syncthreads();
    const __hip_bfloat16* srcp = (k < 6) ? R : xT;
    const int rps = (k < 6) ? 192 : 32;  // rows per (b,l)
    const int ko = (k < 6) ? k * 32 : 0;
#pragma unroll
    for (int i = 0; i < 24; ++i) {       // 6144 ushort4 chunks
      int q = tid + i * 256;
      int rr = q >> 4, ci = q & 15;      // rr = l*32+c
      int l = rr >> 5, c = rr & 31;
      size_t rowg = (size_t)(b * L_DIM + l) * rps + ko + c;
      *(ushort4*)&tile[rr * 64 + ci * 4] =
          *(const ushort4*)&srcp[rowg * V_DIM + w0 + ci * 4];
    }
    __syncthreads();
    const float* Wp = &Wl[((k < 6) ? (k + 1) : 0) * 1024];
    const int base0 = ll[0] * 2048 + wloc[0];
    const int base1 = ll[1] * 2048 + wloc[1];
    const int base2 = ll[2] * 2048 + wloc[2];
#pragma unroll 8
    for (int c = 0; c < 32; ++c) {
      float v0 = __bfloat162float(tile[base0 + c * 64]);
      float v1 = __bfloat162float(tile[base1 + c * 64]);
      float v2 = __bfloat162float(tile[base2 + c * 64]);
#pragma unroll
      for (int o = 0; o < 32; ++o) {
        float wv = Wp[c * 32 + o];
        acc[0][o] += wv * v0;
        acc[1][o] += wv * v1;
        acc[2][o] += wv * v2;
      }
    }
  }
  const size_t obase = (size_t)b * (32 * V_DIM * L_DIM) + (size_t)w0 * L_DIM;
#pragma unroll
  for (int o = 0; o < 32; ++o) {
    size_t base = obase + (size_t)o * (V_DIM * L_DIM);
    out[base + tid] = acc[0][o];
    out[base + tid + 256] = acc[1][o];
    out[base + tid + 512] = acc[2][o];
  }
}

// --------------------------- launcher ------------------------------------
extern "C" void kernel_launch(void* const* d_in, const int* in_sizes, int n_in,
                              void* d_out, int out_size, void* d_ws,
                              size_t ws_size, hipStream_t stream) {
  const float* x = (const float*)d_in[0];
  const float* A1 = (const float*)d_in[1];
  const float* A2 = (const float*)d_in[2];
  const float* nv1 = (const float*)d_in[3];
  const float* nv2 = (const float*)d_in[4];
  const float* W = (const float*)d_in[5];
  const float* bias = (const float*)d_in[6];
  float* out = (float*)d_out;

  char* ws = (char*)d_ws;
  // ws layout (bytes): R 301,989,888 | xT 50,331,648 | BtCat 12,582,912 |
  //                    As 6,291,456 | adp 4,194,304   => total ~375.4 MB
  __hip_bfloat16* R = (__hip_bfloat16*)(ws + 0);
  __hip_bfloat16* xT = (__hip_bfloat16*)(ws + 301989888ull);
  __hip_bfloat16* BtCat = (__hip_bfloat16*)(ws + 352321536ull);
  __hip_bfloat16* As = (__hip_bfloat16*)(ws + 364904448ull);
  float* adp = (float*)(ws + 371195904ull);

  // 1. adaptive adjacency
  adp_kernel<<<dim3(1024), dim3(128), 0, stream>>>(nv1, nv2, adp);
  // 2. bf16 casts: straight (As) + transposed (BtCat slices 0,2,4)
  cast_transpose<<<dim3(16, 16, 3), dim3(256), 0, stream>>>(A1, A2, adp, As, BtCat);
  // 3. squares: BtCat slice 2z+1 = (a^2)^T = At @ As^T   (M=N=K=1024)
  gemm_bt<0><<<dim3(8, 8, 3), dim3(256), 0, stream>>>(
      BtCat, As, BtCat + 1048576ull, 1024, 1024, 1024,
      2097152ll, 1048576ll, 2097152ll);
  // 4. x -> xT bf16
  transpose_x_k<<<dim3(2048), dim3(256), 0, stream>>>(x, xT);
  // 5. main diffusion GEMM: R = xT @ BtCat^T  (M=24576, N=6144, K=1024)
  //    256^2 tile, 8 waves, counted-vmcnt phased pipeline
  gemm256<<<dim3(24, 96), dim3(512), 0, stream>>>(xT, BtCat, R);
  // 6. channel mix + bias -> out
  mix_kernel<<<dim3(16, 64), dim3(256), 0, stream>>>(R, xT, W, bias, out);
}

// Round 2
// 765.560 us; speedup vs baseline: 1.0378x; 1.0018x over previous
//
#include <hip/hip_runtime.h>
#include <hip/hip_bf16.h>

// Problem constants (fixed by reference): B=64, C=32, V=1024, L=12, ORDER=2
// Decomposition:
//   adp = softmax(relu(nv1@nv2), axis=1)
//   Bt_cat[6][1024][1024] bf16:  slice k, row w, col v = G_k[v][w]
//     G = {A1, A1^2, A2, A2^2, adp, adp^2}
//   xT bf16 rows m=(b*12+l)*32+c, cols v   (row-major K=1024)
//   R[m,(k,w)] = sum_v xT[m,v]*G_k[v,w]  stored in layout [b][l][k][c][w] bf16
//   out[b,o,w,l] = bias[o] + sum_c W[o,c]*x[b,c,w,l] + sum_{k,c} W[o,32(k+1)+c]*R_k[b,c,w,l]
//
// R3 change: register-level fragment double-buffering in gemm256. R2's phase
// body consumed its ds_reads right after the same phase's barrier -> lockstep
// waves serialized [LDS drain ~500cy] -> [MFMA 620cy] per phase (measured
// 2869 cy/iter vs ~1400 overlapped). Now every ds_read is issued one full
// phase before its consuming MFMA cluster (af1 pre-read in phase0; next
// iter's bf/af0 pre-read in phase1, explicit A/B register sets, manual x2
// unroll), so lgkm waits are counted and the LDS pipe drains under MFMA.
// vmcnt deepened 8->4 so the cross-iter pre-read of unit (h+1)&3 is
// guaranteed resident (halves <= h+2 retired at end of iter h).

typedef __attribute__((ext_vector_type(8))) short short8;
typedef __attribute__((ext_vector_type(4))) float floatx4;

#define V_DIM 1024
#define L_DIM 12
#define B_DIM 64
#define C_DIM 32

// ---------------- adp: relu + row softmax --------------------------------
__global__ __launch_bounds__(128) void adp_kernel(
    const float* __restrict__ nv1, const float* __restrict__ nv2,
    float* __restrict__ adp) {
  const int v = blockIdx.x, tid = threadIdx.x;
  float n1[10];
#pragma unroll
  for (int i = 0; i < 10; ++i) n1[i] = nv1[v * 10 + i];
  __shared__ float red[128];
  float e[8];
  float lmax = -1e30f;
#pragma unroll
  for (int j = 0; j < 8; ++j) {
    int w = tid + j * 128;
    float s = 0.f;
#pragma unroll
    for (int i = 0; i < 10; ++i) s += n1[i] * nv2[i * V_DIM + w];
    s = fmaxf(s, 0.f);
    e[j] = s;
    lmax = fmaxf(lmax, s);
  }
  red[tid] = lmax; __syncthreads();
  for (int s = 64; s > 0; s >>= 1) {
    if (tid < s) red[tid] = fmaxf(red[tid], red[tid + s]);
    __syncthreads();
  }
  float mx = red[0]; __syncthreads();
  float lsum = 0.f;
#pragma unroll
  for (int j = 0; j < 8; ++j) { e[j] = __expf(e[j] - mx); lsum += e[j]; }
  red[tid] = lsum; __syncthreads();
  for (int s = 64; s > 0; s >>= 1) {
    if (tid < s) red[tid] += red[tid + s];
    __syncthreads();
  }
  float inv = 1.f / red[0];
#pragma unroll
  for (int j = 0; j < 8; ++j) adp[(size_t)v * V_DIM + tid + j * 128] = e[j] * inv;
}

// ------------- cast supports to bf16: straight + transposed ---------------
__global__ __launch_bounds__(256) void cast_transpose(
    const float* __restrict__ A1, const float* __restrict__ A2,
    const float* __restrict__ adp, __hip_bfloat16* __restrict__ As,
    __hip_bfloat16* __restrict__ BtCat) {
  const int z = blockIdx.z;
  const float* src = (z == 0) ? A1 : (z == 1) ? A2 : adp;
  __hip_bfloat16* sdst = As + (size_t)z * V_DIM * V_DIM;
  __hip_bfloat16* tdst = BtCat + (size_t)(2 * z) * V_DIM * V_DIM;
  __shared__ float tile[64][65];
  const int v0 = blockIdx.y * 64, w0 = blockIdx.x * 64;
  const int tc = threadIdx.x & 15, tr = threadIdx.x >> 4;
#pragma unroll
  for (int i = 0; i < 4; ++i) {
    int r = tr + i * 16;
    float4 val = *(const float4*)(src + (size_t)(v0 + r) * V_DIM + w0 + tc * 4);
    tile[r][tc * 4 + 0] = val.x; tile[r][tc * 4 + 1] = val.y;
    tile[r][tc * 4 + 2] = val.z; tile[r][tc * 4 + 3] = val.w;
    __hip_bfloat16* sp = sdst + (size_t)(v0 + r) * V_DIM + w0 + tc * 4;
    sp[0] = __float2bfloat16(val.x); sp[1] = __float2bfloat16(val.y);
    sp[2] = __float2bfloat16(val.z); sp[3] = __float2bfloat16(val.w);
  }
  __syncthreads();
#pragma unroll
  for (int i = 0; i < 4; ++i) {
    int r = tr + i * 16;  // output row = w0 + r
    __hip_bfloat16* tp = tdst + (size_t)(w0 + r) * V_DIM + v0 + tc * 4;
#pragma unroll
    for (int j = 0; j < 4; ++j) tp[j] = __float2bfloat16(tile[tc * 4 + j][r]);
  }
}

// ------------- x [B,C,V,L] fp32 -> xT bf16 rows (b*12+l)*32+c -------------
__global__ __launch_bounds__(256) void transpose_x_k(
    const float* __restrict__ x, __hip_bfloat16* __restrict__ xT) {
  const int bc = blockIdx.x;         // b*32+c
  const int b = bc >> 5, c = bc & 31;
  __shared__ __align__(16) __hip_bfloat16 tile[V_DIM * L_DIM];  // idx v*12+l
  const float4* src = (const float4*)(x + (size_t)bc * (V_DIM * L_DIM));
#pragma unroll
  for (int i = 0; i < 12; ++i) {
    int idx = threadIdx.x + i * 256;  // 3072 float4
    float4 v = src[idx];
    int e = idx * 4;
    tile[e + 0] = __float2bfloat16(v.x); tile[e + 1] = __float2bfloat16(v.y);
    tile[e + 2] = __float2bfloat16(v.z); tile[e + 3] = __float2bfloat16(v.w);
  }
  __syncthreads();
  for (int l = 0; l < L_DIM; ++l) {
    __hip_bfloat16* dst = xT + ((size_t)(b * L_DIM + l) * C_DIM + c) * V_DIM;
    for (int v = threadIdx.x; v < V_DIM; v += 256) dst[v] = tile[v * L_DIM + l];
  }
}

// ---------------- async global->LDS helper --------------------------------
__device__ __forceinline__ void gll16(const __hip_bfloat16* g, __hip_bfloat16* l) {
  __builtin_amdgcn_global_load_lds(
      (const __attribute__((address_space(1))) void*)g,
      (__attribute__((address_space(3))) void*)l, 16, 0, 0);
}

// ---------------- MFMA GEMM (128^2, 2-barrier): squares only --------------
// A [M,K] bf16 row-major, Bt [N,K] bf16 row-major, C row-major bf16 [M,N].
template <int MODE>
__global__ __launch_bounds__(256) void gemm_bt(
    const __hip_bfloat16* __restrict__ Abase,
    const __hip_bfloat16* __restrict__ Btbase,
    __hip_bfloat16* __restrict__ Cbase, int M, int N, int K,
    long long aStride, long long bStride, long long cStride) {
  const __hip_bfloat16* A = Abase + (size_t)blockIdx.z * aStride;
  const __hip_bfloat16* Bt = Btbase + (size_t)blockIdx.z * bStride;
  __hip_bfloat16* C = Cbase + (size_t)blockIdx.z * cStride;
  __shared__ __align__(16) __hip_bfloat16 lA[128 * 64];
  __shared__ __align__(16) __hip_bfloat16 lB[128 * 64];
  const int tid = threadIdx.x;
  const int wv = tid >> 6, lane = tid & 63;
  const int wm = wv >> 1, wn = wv & 1;
  const int m0 = blockIdx.y * 128, n0 = blockIdx.x * 128;
  const int lrow = lane >> 3, lcol = lane & 7;  // staging: 8 rows / wave-instr
  const int gcol = lcol ^ (lrow & 7);           // XOR bank swizzle
  const int fr = lane & 15, quad = lane >> 4;   // fragment coords
  const int sw = fr & 7;                        // read-side swizzle key

  floatx4 acc[4][4];
#pragma unroll
  for (int i = 0; i < 4; ++i)
#pragma unroll
    for (int j = 0; j < 4; ++j) acc[i][j] = (floatx4){0.f, 0.f, 0.f, 0.f};

  for (int kt = 0; kt < K; kt += 64) {
    __syncthreads();  // previous tile fully consumed
#pragma unroll
    for (int i = 0; i < 4; ++i) {
      int r0 = (wv * 4 + i) * 8;
      gll16(A + (size_t)(m0 + r0 + lrow) * K + kt + gcol * 8, &lA[r0 * 64]);
      gll16(Bt + (size_t)(n0 + r0 + lrow) * K + kt + gcol * 8, &lB[r0 * 64]);
    }
    __syncthreads();  // drains vmcnt(0): staged data visible
#pragma unroll
    for (int ks = 0; ks < 2; ++ks) {
      const int chunk = (ks * 4 + quad) ^ sw;   // swizzled K-chunk slot
      short8 af[4], bfr[4];
#pragma unroll
      for (int t = 0; t < 4; ++t) {
        af[t] = *(const short8*)&lA[(wm * 64 + t * 16 + fr) * 64 + chunk * 8];
        bfr[t] = *(const short8*)&lB[(wn * 64 + t * 16 + fr) * 64 + chunk * 8];
      }
#pragma unroll
      for (int i = 0; i < 4; ++i)
#pragma unroll
        for (int j = 0; j < 4; ++j)
          acc[i][j] = __builtin_amdgcn_mfma_f32_16x16x32_bf16(af[i], bfr[j], acc[i][j], 0, 0, 0);
    }
  }
  // epilogue: C/D layout col=lane&15, row=quad*4+reg (m89-verified)
#pragma unroll
  for (int i = 0; i < 4; ++i) {
#pragma unroll
    for (int j = 0; j < 4; ++j) {
      int mb = m0 + wm * 64 + i * 16 + quad * 4;
      int n = n0 + wn * 64 + j * 16 + fr;
#pragma unroll
      for (int r = 0; r < 4; ++r) {
        int m = mb + r;
        float val = acc[i][j][r];
        size_t idx;
        if (MODE == 0) {
          idx = (size_t)m * N + n;
        } else {
          int c = m & 31, bl = m >> 5, k = n >> 10, w = n & 1023;
          idx = (((size_t)bl * 6 + k) * 32 + c) * 1024 + w;
        }
        C[idx] = __float2bfloat16(val);
      }
    }
  }
}

// ------------- main diffusion GEMM: 256^2, 8-wave, phased pipeline --------
// A = xT [24576][1024], Bt = BtCat [6144][1024]; C = R scatter layout.
// 4-unit LDS ring (unit = A 256x32 + B 256x32 bf16 = 32 KB), staged 3
// K-halves ahead.  Register fragment double-buffering: each ds_read is
// issued one full MFMA phase before its consuming cluster:
//   P0(h): read af1 (rows 64..127 of unit h&3) | stage A(h+3) | bar |
//          MFMA acc[0..3] (bf, af0)            | bar
//   P1(h): read bf',af0' from unit (h+1)&3     | stage B(h+3) | vmcnt | bar |
//          MFMA acc[4..7] (bf, af1)            | bar
// vmcnt(4) per iter retires half h+2 -> units h+1,h+2 resident at the next
// barrier, making the cross-iter pre-read race-free. Explicit A/B register
// sets + manual x2 unroll keep all frag indices compile-time (rule #20).
__global__ __launch_bounds__(512, 2) void gemm256(
    const __hip_bfloat16* __restrict__ A,
    const __hip_bfloat16* __restrict__ Bt,
    __hip_bfloat16* __restrict__ C) {
  constexpr int K = 1024;
  constexpr int NH = K / 32;  // 32 K-halves
  __shared__ __align__(16) __hip_bfloat16 sA[4][8192];  // [unit][row*32+col]
  __shared__ __align__(16) __hip_bfloat16 sB[4][8192];
  const int tid = threadIdx.x;
  const int wv = tid >> 6, lane = tid & 63;
  const int wm = wv >> 2, wn = wv & 3;          // 2x4 wave grid, 128x64 C/wave
  const int fr = lane & 15, quad = lane >> 4;
  const int rslot = (quad ^ ((fr >> 1) & 3)) << 3;   // swizzled 8-elem slot
  const int aoff = (wm * 128 + fr) * 32 + rslot;     // A-frag elem offset
  const int boff = (wn * 64 + fr) * 32 + rslot;      // B-frag elem offset
  const int m0 = blockIdx.y * 256, n0 = blockIdx.x * 256;
  const int srow = wv * 32 + (lane >> 2);            // staging local row
  const int gch = ((lane & 3) ^ ((lane >> 3) & 3)) << 3;  // pre-swizzled col
  const __hip_bfloat16* Ag = A + (size_t)(m0 + srow) * K + gch;
  const __hip_bfloat16* Bg = Bt + (size_t)(n0 + srow) * K + gch;
  const int sbase = (wv * 32) * 32;                  // LDS elem base; +512 = inst1

  floatx4 acc[8][4];
#pragma unroll
  for (int i = 0; i < 8; ++i)
#pragma unroll
    for (int j = 0; j < 4; ++j) acc[i][j] = (floatx4){0.f, 0.f, 0.f, 0.f};

  // prologue: stage halves 0..2 (order per half: A0,A1,B0,B1)
#pragma unroll
  for (int hp = 0; hp < 3; ++hp) {
    gll16(Ag + hp * 32, &sA[hp][sbase]);
    gll16(Ag + (size_t)16 * K + hp * 32, &sA[hp][sbase + 512]);
    gll16(Bg + hp * 32, &sB[hp][sbase]);
    gll16(Bg + (size_t)16 * K + hp * 32, &sB[hp][sbase + 512]);
  }
  asm volatile("s_waitcnt vmcnt(4)" ::: "memory");   // halves 0,1 resident
  __builtin_amdgcn_s_barrier();

  short8 bfA[4], af0A[4], bfB[4], af0B[4], af1[4];
#pragma unroll
  for (int j = 0; j < 4; ++j) bfA[j] = *(const short8*)&sB[0][boff + j * 512];
#pragma unroll
  for (int i = 0; i < 4; ++i) af0A[i] = *(const short8*)&sA[0][aoff + i * 512];

#define P0(h, bfC, af0C)                                                     \
  {                                                                          \
    const int u_ = (h) & 3;                                                  \
    _Pragma("unroll") for (int i = 0; i < 4; ++i)                            \
        af1[i] = *(const short8*)&sA[u_][aoff + (4 + i) * 512];              \
    if ((h) + 3 < NH) {                                                      \
      const int u3_ = ((h) + 3) & 3;                                         \
      gll16(Ag + ((h) + 3) * 32, &sA[u3_][sbase]);                           \
      gll16(Ag + (size_t)16 * K + ((h) + 3) * 32, &sA[u3_][sbase + 512]);    \
    }                                                                        \
    __builtin_amdgcn_s_barrier();                                            \
    __builtin_amdgcn_s_setprio(1);                                           \
    _Pragma("unroll") for (int i = 0; i < 4; ++i)                            \
        _Pragma("unroll") for (int j = 0; j < 4; ++j)                        \
            acc[i][j] = __builtin_amdgcn_mfma_f32_16x16x32_bf16(             \
                af0C[i], bfC[j], acc[i][j], 0, 0, 0);                        \
    __builtin_amdgcn_s_setprio(0);                                           \
    __builtin_amdgcn_s_barrier();                                            \
  }

#define P1(h, bfC, bfN, af0N)                                                \
  {                                                                          \
    if ((h) + 1 < NH) {                                                      \
      const int un_ = ((h) + 1) & 3;                                         \
      _Pragma("unroll") for (int j = 0; j < 4; ++j)                          \
          bfN[j] = *(const short8*)&sB[un_][boff + j * 512];                 \
      _Pragma("unroll") for (int i = 0; i < 4; ++i)                          \
          af0N[i] = *(const short8*)&sA[un_][aoff + i * 512];                \
    }                                                                        \
    if ((h) + 3 < NH) {                                                      \
      const int u3_ = ((h) + 3) & 3;                                         \
      gll16(Bg + ((h) + 3) * 32, &sB[u3_][sbase]);                           \
      gll16(Bg + (size_t)16 * K + ((h) + 3) * 32, &sB[u3_][sbase + 512]);    \
    }                                                                        \
    if ((h) < NH - 3) {                                                      \
      asm volatile("s_waitcnt vmcnt(4)" ::: "memory");                       \
    } else if ((h) == NH - 3) {                                              \
      asm volatile("s_waitcnt vmcnt(0)" ::: "memory");                       \
    }                                                                        \
    __builtin_amdgcn_s_barrier();                                            \
    __builtin_amdgcn_s_setprio(1);                                           \
    _Pragma("unroll") for (int i = 0; i < 4; ++i)                            \
        _Pragma("unroll") for (int j = 0; j < 4; ++j)                        \
            acc[4 + i][j] = __builtin_amdgcn_mfma_f32_16x16x32_bf16(         \
                af1[i], bfC[j], acc[4 + i][j], 0, 0, 0);                     \
    __builtin_amdgcn_s_setprio(0);                                           \
    __builtin_amdgcn_s_barrier();                                            \
  }

  for (int hh = 0; hh < NH; hh += 2) {
    P0(hh, bfA, af0A)
    P1(hh, bfA, bfB, af0B)
    P0(hh + 1, bfB, af0B)
    P1(hh + 1, bfB, bfA, af0A)
  }
#undef P0
#undef P1

  // epilogue: R-layout scatter (same mapping as gemm_bt<1>)
#pragma unroll
  for (int i = 0; i < 8; ++i) {
#pragma unroll
    for (int j = 0; j < 4; ++j) {
      int mb = m0 + wm * 128 + i * 16 + quad * 4;
      int n = n0 + wn * 64 + j * 16 + fr;
      int k = n >> 10, w = n & 1023;
#pragma unroll
      for (int r = 0; r < 4; ++r) {
        int m = mb + r;
        int c = m & 31, bl = m >> 5;
        size_t idx = (((size_t)bl * 6 + k) * 32 + c) * 1024 + w;
        C[idx] = __float2bfloat16(acc[i][j][r]);
      }
    }
  }
}

// ---------------- mix: out = W * concat(x, hops) + b ----------------------
__global__ __launch_bounds__(256) void mix_kernel(
    const __hip_bfloat16* __restrict__ R, const __hip_bfloat16* __restrict__ xT,
    const float* __restrict__ W, const float* __restrict__ bias,
    float* __restrict__ out) {
  const int b = blockIdx.y, wt = blockIdx.x;
  const int tid = threadIdx.x;
  __shared__ __align__(16) __hip_bfloat16 tile[L_DIM * C_DIM * 64];  // [l][c][w64]
  __shared__ float Wl[7 * 32 * 32];  // Wl[(p*32+c)*32+o] = W[o][p*32+c]
  for (int i = tid; i < 7168; i += 256) {
    int o = i / 224, cc = i - o * 224;
    Wl[cc * 32 + o] = W[i];
  }
  float acc[3][32];
#pragma unroll
  for (int pt = 0; pt < 3; ++pt)
#pragma unroll
    for (int o = 0; o < 32; ++o) acc[pt][o] = bias[o];
  int wloc[3], ll[3];
#pragma unroll
  for (int pt = 0; pt < 3; ++pt) {
    int wl = tid + pt * 256;
    wloc[pt] = wl / 12;
    ll[pt] = wl - wloc[pt] * 12;
  }
  const int w0 = wt * 64;
  for (int k = 0; k < 7; ++k) {
    __syncthreads();
    const __hip_bfloat16* srcp = (k < 6) ? R : xT;
    const int rps = (k < 6) ? 192 : 32;  // rows per (b,l)
    const int ko = (k < 6) ? k * 32 : 0;
#pragma unroll
    for (int i = 0; i < 24; ++i) {       // 6144 ushort4 chunks
      int q = tid + i * 256;
      int rr = q >> 4, ci = q & 15;      // rr = l*32+c
      int l = rr >> 5, c = rr & 31;
      size_t rowg = (size_t)(b * L_DIM + l) * rps + ko + c;
      *(ushort4*)&tile[rr * 64 + ci * 4] =
          *(const ushort4*)&srcp[rowg * V_DIM + w0 + ci * 4];
    }
    __syncthreads();
    const float* Wp = &Wl[((k < 6) ? (k + 1) : 0) * 1024];
    const int base0 = ll[0] * 2048 + wloc[0];
    const int base1 = ll[1] * 2048 + wloc[1];
    const int base2 = ll[2] * 2048 + wloc[2];
#pragma unroll 8
    for (int c = 0; c < 32; ++c) {
      float v0 = __bfloat162float(tile[base0 + c * 64]);
      float v1 = __bfloat162float(tile[base1 + c * 64]);
      float v2 = __bfloat162float(tile[base2 + c * 64]);
#pragma unroll
      for (int o = 0; o < 32; ++o) {
        float wv = Wp[c * 32 + o];
        acc[0][o] += wv * v0;
        acc[1][o] += wv * v1;
        acc[2][o] += wv * v2;
      }
    }
  }
  const size_t obase = (size_t)b * (32 * V_DIM * L_DIM) + (size_t)w0 * L_DIM;
#pragma unroll
  for (int o = 0; o < 32; ++o) {
    size_t base = obase + (size_t)o * (V_DIM * L_DIM);
    out[base + tid] = acc[0][o];
    out[base + tid + 256] = acc[1][o];
    out[base + tid + 512] = acc[2][o];
  }
}

// --------------------------- launcher ------------------------------------
extern "C" void kernel_launch(void* const* d_in, const int* in_sizes, int n_in,
                              void* d_out, int out_size, void* d_ws,
                              size_t ws_size, hipStream_t stream) {
  const float* x = (const float*)d_in[0];
  const float* A1 = (const float*)d_in[1];
  const float* A2 = (const float*)d_in[2];
  const float* nv1 = (const float*)d_in[3];
  const float* nv2 = (const float*)d_in[4];
  const float* W = (const float*)d_in[5];
  const float* bias = (const float*)d_in[6];
  float* out = (float*)d_out;

  char* ws = (char*)d_ws;
  // ws layout (bytes): R 301,989,888 | xT 50,331,648 | BtCat 12,582,912 |
  //                    As 6,291,456 | adp 4,194,304   => total ~375.4 MB
  __hip_bfloat16* R = (__hip_bfloat16*)(ws + 0);
  __hip_bfloat16* xT = (__hip_bfloat16*)(ws + 301989888ull);
  __hip_bfloat16* BtCat = (__hip_bfloat16*)(ws + 352321536ull);
  __hip_bfloat16* As = (__hip_bfloat16*)(ws + 364904448ull);
  float* adp = (float*)(ws + 371195904ull);

  // 1. adaptive adjacency
  adp_kernel<<<dim3(1024), dim3(128), 0, stream>>>(nv1, nv2, adp);
  // 2. bf16 casts: straight (As) + transposed (BtCat slices 0,2,4)
  cast_transpose<<<dim3(16, 16, 3), dim3(256), 0, stream>>>(A1, A2, adp, As, BtCat);
  // 3. squares: BtCat slice 2z+1 = (a^2)^T = At @ As^T   (M=N=K=1024)
  gemm_bt<0><<<dim3(8, 8, 3), dim3(256), 0, stream>>>(
      BtCat, As, BtCat + 1048576ull, 1024, 1024, 1024,
      2097152ll, 1048576ll, 2097152ll);
  // 4. x -> xT bf16
  transpose_x_k<<<dim3(2048), dim3(256), 0, stream>>>(x, xT);
  // 5. main diffusion GEMM: R = xT @ BtCat^T  (M=24576, N=6144, K=1024)
  //    256^2 tile, 8 waves, reg-double-buffered counted-vmcnt pipeline
  gemm256<<<dim3(24, 96), dim3(512), 0, stream>>>(xT, BtCat, R);
  // 6. channel mix + bias -> out
  mix_kernel<<<dim3(16, 64), dim3(256), 0, stream>>>(R, xT, W, bias, out);
}

// Round 3
// 758.000 us; speedup vs baseline: 1.0481x; 1.0100x over previous
//
#include <hip/hip_runtime.h>
#include <hip/hip_bf16.h>

// Problem constants (fixed by reference): B=64, C=32, V=1024, L=12, ORDER=2
// Decomposition:
//   adp = softmax(relu(nv1@nv2), axis=1)
//   Bt_cat[6][1024][1024] bf16:  slice k, row w, col v = G_k[v][w]
//     G = {A1, A1^2, A2, A2^2, adp, adp^2}
//   xT bf16 rows m=(b*12+l)*32+c, cols v   (row-major K=1024)
//   R[m,(k,w)] = sum_v xT[m,v]*G_k[v,w]  stored in layout [b][l][k][c][w] bf16
//   out[b,o,w,l] = bias[o] + sum_c W[o,c]*x[b,c,w,l] + sum_{k,c} W[o,32(k+1)+c]*R_k[b,c,w,l]
//
// R4 change: main GEMM restructured for cross-block TLP. R2/R3's 256^2
// 1-block/CU design was phase-serial (measured: phase = MFMA 620 + LDS 380 +
// VALU 270 cyc, fully additive) because all 8 waves share one barrier domain
// -> matrix pipe idle during every memory window. Now: 256x128 tile, 4 waves
// (2x2), 3-unit BK=32 LDS ring (72 KiB) -> 2 independent blocks/CU
// (launch_bounds(256,2)); one barrier per iter; counted vmcnt(6); setprio
// around the MFMA cluster. Block A's memory window overlaps block B's MFMA.

typedef __attribute__((ext_vector_type(8))) short short8;
typedef __attribute__((ext_vector_type(4))) float floatx4;

#define V_DIM 1024
#define L_DIM 12
#define B_DIM 64
#define C_DIM 32

// ---------------- adp: relu + row softmax --------------------------------
__global__ __launch_bounds__(128) void adp_kernel(
    const float* __restrict__ nv1, const float* __restrict__ nv2,
    float* __restrict__ adp) {
  const int v = blockIdx.x, tid = threadIdx.x;
  float n1[10];
#pragma unroll
  for (int i = 0; i < 10; ++i) n1[i] = nv1[v * 10 + i];
  __shared__ float red[128];
  float e[8];
  float lmax = -1e30f;
#pragma unroll
  for (int j = 0; j < 8; ++j) {
    int w = tid + j * 128;
    float s = 0.f;
#pragma unroll
    for (int i = 0; i < 10; ++i) s += n1[i] * nv2[i * V_DIM + w];
    s = fmaxf(s, 0.f);
    e[j] = s;
    lmax = fmaxf(lmax, s);
  }
  red[tid] = lmax; __syncthreads();
  for (int s = 64; s > 0; s >>= 1) {
    if (tid < s) red[tid] = fmaxf(red[tid], red[tid + s]);
    __syncthreads();
  }
  float mx = red[0]; __syncthreads();
  float lsum = 0.f;
#pragma unroll
  for (int j = 0; j < 8; ++j) { e[j] = __expf(e[j] - mx); lsum += e[j]; }
  red[tid] = lsum; __syncthreads();
  for (int s = 64; s > 0; s >>= 1) {
    if (tid < s) red[tid] += red[tid + s];
    __syncthreads();
  }
  float inv = 1.f / red[0];
#pragma unroll
  for (int j = 0; j < 8; ++j) adp[(size_t)v * V_DIM + tid + j * 128] = e[j] * inv;
}

// ------------- cast supports to bf16: straight + transposed ---------------
__global__ __launch_bounds__(256) void cast_transpose(
    const float* __restrict__ A1, const float* __restrict__ A2,
    const float* __restrict__ adp, __hip_bfloat16* __restrict__ As,
    __hip_bfloat16* __restrict__ BtCat) {
  const int z = blockIdx.z;
  const float* src = (z == 0) ? A1 : (z == 1) ? A2 : adp;
  __hip_bfloat16* sdst = As + (size_t)z * V_DIM * V_DIM;
  __hip_bfloat16* tdst = BtCat + (size_t)(2 * z) * V_DIM * V_DIM;
  __shared__ float tile[64][65];
  const int v0 = blockIdx.y * 64, w0 = blockIdx.x * 64;
  const int tc = threadIdx.x & 15, tr = threadIdx.x >> 4;
#pragma unroll
  for (int i = 0; i < 4; ++i) {
    int r = tr + i * 16;
    float4 val = *(const float4*)(src + (size_t)(v0 + r) * V_DIM + w0 + tc * 4);
    tile[r][tc * 4 + 0] = val.x; tile[r][tc * 4 + 1] = val.y;
    tile[r][tc * 4 + 2] = val.z; tile[r][tc * 4 + 3] = val.w;
    __hip_bfloat16* sp = sdst + (size_t)(v0 + r) * V_DIM + w0 + tc * 4;
    sp[0] = __float2bfloat16(val.x); sp[1] = __float2bfloat16(val.y);
    sp[2] = __float2bfloat16(val.z); sp[3] = __float2bfloat16(val.w);
  }
  __syncthreads();
#pragma unroll
  for (int i = 0; i < 4; ++i) {
    int r = tr + i * 16;  // output row = w0 + r
    __hip_bfloat16* tp = tdst + (size_t)(w0 + r) * V_DIM + v0 + tc * 4;
#pragma unroll
    for (int j = 0; j < 4; ++j) tp[j] = __float2bfloat16(tile[tc * 4 + j][r]);
  }
}

// ------------- x [B,C,V,L] fp32 -> xT bf16 rows (b*12+l)*32+c -------------
__global__ __launch_bounds__(256) void transpose_x_k(
    const float* __restrict__ x, __hip_bfloat16* __restrict__ xT) {
  const int bc = blockIdx.x;         // b*32+c
  const int b = bc >> 5, c = bc & 31;
  __shared__ __align__(16) __hip_bfloat16 tile[V_DIM * L_DIM];  // idx v*12+l
  const float4* src = (const float4*)(x + (size_t)bc * (V_DIM * L_DIM));
#pragma unroll
  for (int i = 0; i < 12; ++i) {
    int idx = threadIdx.x + i * 256;  // 3072 float4
    float4 v = src[idx];
    int e = idx * 4;
    tile[e + 0] = __float2bfloat16(v.x); tile[e + 1] = __float2bfloat16(v.y);
    tile[e + 2] = __float2bfloat16(v.z); tile[e + 3] = __float2bfloat16(v.w);
  }
  __syncthreads();
  for (int l = 0; l < L_DIM; ++l) {
    __hip_bfloat16* dst = xT + ((size_t)(b * L_DIM + l) * C_DIM + c) * V_DIM;
    for (int v = threadIdx.x; v < V_DIM; v += 256) dst[v] = tile[v * L_DIM + l];
  }
}

// ---------------- async global->LDS helper --------------------------------
__device__ __forceinline__ void gll16(const __hip_bfloat16* g, __hip_bfloat16* l) {
  __builtin_amdgcn_global_load_lds(
      (const __attribute__((address_space(1))) void*)g,
      (__attribute__((address_space(3))) void*)l, 16, 0, 0);
}

// ---------------- MFMA GEMM (128^2, 2-barrier): squares only --------------
// A [M,K] bf16 row-major, Bt [N,K] bf16 row-major, C row-major bf16 [M,N].
template <int MODE>
__global__ __launch_bounds__(256) void gemm_bt(
    const __hip_bfloat16* __restrict__ Abase,
    const __hip_bfloat16* __restrict__ Btbase,
    __hip_bfloat16* __restrict__ Cbase, int M, int N, int K,
    long long aStride, long long bStride, long long cStride) {
  const __hip_bfloat16* A = Abase + (size_t)blockIdx.z * aStride;
  const __hip_bfloat16* Bt = Btbase + (size_t)blockIdx.z * bStride;
  __hip_bfloat16* C = Cbase + (size_t)blockIdx.z * cStride;
  __shared__ __align__(16) __hip_bfloat16 lA[128 * 64];
  __shared__ __align__(16) __hip_bfloat16 lB[128 * 64];
  const int tid = threadIdx.x;
  const int wv = tid >> 6, lane = tid & 63;
  const int wm = wv >> 1, wn = wv & 1;
  const int m0 = blockIdx.y * 128, n0 = blockIdx.x * 128;
  const int lrow = lane >> 3, lcol = lane & 7;  // staging: 8 rows / wave-instr
  const int gcol = lcol ^ (lrow & 7);           // XOR bank swizzle
  const int fr = lane & 15, quad = lane >> 4;   // fragment coords
  const int sw = fr & 7;                        // read-side swizzle key

  floatx4 acc[4][4];
#pragma unroll
  for (int i = 0; i < 4; ++i)
#pragma unroll
    for (int j = 0; j < 4; ++j) acc[i][j] = (floatx4){0.f, 0.f, 0.f, 0.f};

  for (int kt = 0; kt < K; kt += 64) {
    __syncthreads();  // previous tile fully consumed
#pragma unroll
    for (int i = 0; i < 4; ++i) {
      int r0 = (wv * 4 + i) * 8;
      gll16(A + (size_t)(m0 + r0 + lrow) * K + kt + gcol * 8, &lA[r0 * 64]);
      gll16(Bt + (size_t)(n0 + r0 + lrow) * K + kt + gcol * 8, &lB[r0 * 64]);
    }
    __syncthreads();  // drains vmcnt(0): staged data visible
#pragma unroll
    for (int ks = 0; ks < 2; ++ks) {
      const int chunk = (ks * 4 + quad) ^ sw;   // swizzled K-chunk slot
      short8 af[4], bfr[4];
#pragma unroll
      for (int t = 0; t < 4; ++t) {
        af[t] = *(const short8*)&lA[(wm * 64 + t * 16 + fr) * 64 + chunk * 8];
        bfr[t] = *(const short8*)&lB[(wn * 64 + t * 16 + fr) * 64 + chunk * 8];
      }
#pragma unroll
      for (int i = 0; i < 4; ++i)
#pragma unroll
        for (int j = 0; j < 4; ++j)
          acc[i][j] = __builtin_amdgcn_mfma_f32_16x16x32_bf16(af[i], bfr[j], acc[i][j], 0, 0, 0);
    }
  }
  // epilogue: C/D layout col=lane&15, row=quad*4+reg (m89-verified)
#pragma unroll
  for (int i = 0; i < 4; ++i) {
#pragma unroll
    for (int j = 0; j < 4; ++j) {
      int mb = m0 + wm * 64 + i * 16 + quad * 4;
      int n = n0 + wn * 64 + j * 16 + fr;
#pragma unroll
      for (int r = 0; r < 4; ++r) {
        int m = mb + r;
        float val = acc[i][j][r];
        size_t idx;
        if (MODE == 0) {
          idx = (size_t)m * N + n;
        } else {
          int c = m & 31, bl = m >> 5, k = n >> 10, w = n & 1023;
          idx = (((size_t)bl * 6 + k) * 32 + c) * 1024 + w;
        }
        C[idx] = __float2bfloat16(val);
      }
    }
  }
}

// ------------- main diffusion GEMM: 256x128, 4 waves, 2 blocks/CU ---------
// A = xT [24576][1024], Bt = BtCat [6144][1024]; C = R scatter layout.
// 3-unit LDS ring (unit = A 256x32 + B 128x32 bf16 = 24 KB, 72 KiB total),
// staged 2 K-steps ahead. Per iter:
//   {12 ds_read_b128 (unit h%3) | STAGE(h+2 -> unit (h+2)%3, 6 gll16/thr)
//    -> setprio(1) 32 MFMA setprio(0) -> vmcnt(6) -> s_barrier}
// One barrier/iter is sufficient: iter-h ds_reads retire before iter-h MFMA
// issue (lgkm dep), so at bar(h) all reads of unit h%3 are done, and the
// next rewrite of that unit (STAGE in iter h+1) is issued after bar(h).
// vmcnt(6) after the MFMA cluster retires half h+1 (issued iter h-1, ~1.5
// iters of slack); vmcnt(0) only at the tail. 2 resident blocks per CU
// anti-phase on the matrix pipe: one block's staging/LDS window overlaps
// the other's MFMA cluster (the TLP the 1-block/CU design lacked).
__global__ __launch_bounds__(256, 2) void gemm256(
    const __hip_bfloat16* __restrict__ A,
    const __hip_bfloat16* __restrict__ Bt,
    __hip_bfloat16* __restrict__ C) {
  constexpr int K = 1024;
  constexpr int NH = K / 32;  // 32 K-steps
  __shared__ __align__(16) __hip_bfloat16 sA[3][256 * 32];  // 16 KB/unit
  __shared__ __align__(16) __hip_bfloat16 sB[3][128 * 32];  //  8 KB/unit
  const int tid = threadIdx.x;
  const int wv = tid >> 6, lane = tid & 63;
  const int wm = wv >> 1, wn = wv & 1;          // 2x2 wave grid, 128x64/wave
  const int fr = lane & 15, quad = lane >> 4;
  const int rslot = (quad ^ ((fr >> 1) & 3)) << 3;   // swizzled 8-elem slot
  const int aoff = (wm * 128 + fr) * 32 + rslot;     // A-frag elem offset
  const int boff = (wn * 64 + fr) * 32 + rslot;      // B-frag elem offset
  const int m0 = blockIdx.y * 256, n0 = blockIdx.x * 128;
  // staging: 16-row groups; lane l -> row (l>>2), slot (l&3) (gll16 linear
  // map), global chunk pre-swizzled with key (row>>1)&3 = (l>>3)&3.
  const int gch = ((lane & 3) ^ ((lane >> 3) & 3)) << 3;
  const __hip_bfloat16* Ag = A + (size_t)(m0 + wv * 16 + (lane >> 2)) * K + gch;
  const __hip_bfloat16* Bg = Bt + (size_t)(n0 + wv * 16 + (lane >> 2)) * K + gch;
  const int sb = (wv * 16) * 32;                     // LDS elem base per wave

  floatx4 acc[8][4];
#pragma unroll
  for (int i = 0; i < 8; ++i)
#pragma unroll
    for (int j = 0; j < 4; ++j) acc[i][j] = (floatx4){0.f, 0.f, 0.f, 0.f};

  // A: 4 instr/thread (rows j*64 + wv*16 + (l>>2)); B: 2 instr/thread.
#define STAGE(hp, ur)                                                        \
  {                                                                          \
    _Pragma("unroll") for (int j = 0; j < 4; ++j)                            \
        gll16(Ag + (size_t)(j * 64) * K + (hp) * 32, &sA[ur][sb + j * 2048]);\
    _Pragma("unroll") for (int j = 0; j < 2; ++j)                            \
        gll16(Bg + (size_t)(j * 64) * K + (hp) * 32, &sB[ur][sb + j * 2048]);\
  }

  // prologue: stage K-steps 0,1
  STAGE(0, 0)
  STAGE(1, 1)
  asm volatile("s_waitcnt vmcnt(6)" ::: "memory");   // step 0 resident
  __builtin_amdgcn_s_barrier();

  int u = 0, us = 2;
  for (int h = 0; h < NH; ++h) {
    short8 af[8], bf[4];
#pragma unroll
    for (int j = 0; j < 4; ++j) bf[j] = *(const short8*)&sB[u][boff + j * 512];
#pragma unroll
    for (int i = 0; i < 8; ++i) af[i] = *(const short8*)&sA[u][aoff + i * 512];
    if (h < NH - 2) STAGE(h + 2, us)
    __builtin_amdgcn_s_setprio(1);
#pragma unroll
    for (int i = 0; i < 8; ++i)
#pragma unroll
      for (int j = 0; j < 4; ++j)
        acc[i][j] = __builtin_amdgcn_mfma_f32_16x16x32_bf16(af[i], bf[j], acc[i][j], 0, 0, 0);
    __builtin_amdgcn_s_setprio(0);
    if (h < NH - 2) {
      asm volatile("s_waitcnt vmcnt(6)" ::: "memory");  // step h+1 resident
    } else if (h == NH - 2) {
      asm volatile("s_waitcnt vmcnt(0)" ::: "memory");
    }
    __builtin_amdgcn_s_barrier();
    u = (u == 2) ? 0 : u + 1;
    us = (us == 2) ? 0 : us + 1;
  }
#undef STAGE

  // epilogue: R-layout scatter (same mapping as gemm_bt<1>)
#pragma unroll
  for (int i = 0; i < 8; ++i) {
#pragma unroll
    for (int j = 0; j < 4; ++j) {
      int mb = m0 + wm * 128 + i * 16 + quad * 4;
      int n = n0 + wn * 64 + j * 16 + fr;
      int k = n >> 10, w = n & 1023;
#pragma unroll
      for (int r = 0; r < 4; ++r) {
        int m = mb + r;
        int c = m & 31, bl = m >> 5;
        size_t idx = (((size_t)bl * 6 + k) * 32 + c) * 1024 + w;
        C[idx] = __float2bfloat16(acc[i][j][r]);
      }
    }
  }
}

// ---------------- mix: out = W * concat(x, hops) + b ----------------------
__global__ __launch_bounds__(256) void mix_kernel(
    const __hip_bfloat16* __restrict__ R, const __hip_bfloat16* __restrict__ xT,
    const float* __restrict__ W, const float* __restrict__ bias,
    float* __restrict__ out) {
  const int b = blockIdx.y, wt = blockIdx.x;
  const int tid = threadIdx.x;
  __shared__ __align__(16) __hip_bfloat16 tile[L_DIM * C_DIM * 64];  // [l][c][w64]
  __shared__ float Wl[7 * 32 * 32];  // Wl[(p*32+c)*32+o] = W[o][p*32+c]
  for (int i = tid; i < 7168; i += 256) {
    int o = i / 224, cc = i - o * 224;
    Wl[cc * 32 + o] = W[i];
  }
  float acc[3][32];
#pragma unroll
  for (int pt = 0; pt < 3; ++pt)
#pragma unroll
    for (int o = 0; o < 32; ++o) acc[pt][o] = bias[o];
  int wloc[3], ll[3];
#pragma unroll
  for (int pt = 0; pt < 3; ++pt) {
    int wl = tid + pt * 256;
    wloc[pt] = wl / 12;
    ll[pt] = wl - wloc[pt] * 12;
  }
  const int w0 = wt * 64;
  for (int k = 0; k < 7; ++k) {
    __syncthreads();
    const __hip_bfloat16* srcp = (k < 6) ? R : xT;
    const int rps = (k < 6) ? 192 : 32;  // rows per (b,l)
    const int ko = (k < 6) ? k * 32 : 0;
#pragma unroll
    for (int i = 0; i < 24; ++i) {       // 6144 ushort4 chunks
      int q = tid + i * 256;
      int rr = q >> 4, ci = q & 15;      // rr = l*32+c
      int l = rr >> 5, c = rr & 31;
      size_t rowg = (size_t)(b * L_DIM + l) * rps + ko + c;
      *(ushort4*)&tile[rr * 64 + ci * 4] =
          *(const ushort4*)&srcp[rowg * V_DIM + w0 + ci * 4];
    }
    __syncthreads();
    const float* Wp = &Wl[((k < 6) ? (k + 1) : 0) * 1024];
    const int base0 = ll[0] * 2048 + wloc[0];
    const int base1 = ll[1] * 2048 + wloc[1];
    const int base2 = ll[2] * 2048 + wloc[2];
#pragma unroll 8
    for (int c = 0; c < 32; ++c) {
      float v0 = __bfloat162float(tile[base0 + c * 64]);
      float v1 = __bfloat162float(tile[base1 + c * 64]);
      float v2 = __bfloat162float(tile[base2 + c * 64]);
#pragma unroll
      for (int o = 0; o < 32; ++o) {
        float wv = Wp[c * 32 + o];
        acc[0][o] += wv * v0;
        acc[1][o] += wv * v1;
        acc[2][o] += wv * v2;
      }
    }
  }
  const size_t obase = (size_t)b * (32 * V_DIM * L_DIM) + (size_t)w0 * L_DIM;
#pragma unroll
  for (int o = 0; o < 32; ++o) {
    size_t base = obase + (size_t)o * (V_DIM * L_DIM);
    out[base + tid] = acc[0][o];
    out[base + tid + 256] = acc[1][o];
    out[base + tid + 512] = acc[2][o];
  }
}

// --------------------------- launcher ------------------------------------
extern "C" void kernel_launch(void* const* d_in, const int* in_sizes, int n_in,
                              void* d_out, int out_size, void* d_ws,
                              size_t ws_size, hipStream_t stream) {
  const float* x = (const float*)d_in[0];
  const float* A1 = (const float*)d_in[1];
  const float* A2 = (const float*)d_in[2];
  const float* nv1 = (const float*)d_in[3];
  const float* nv2 = (const float*)d_in[4];
  const float* W = (const float*)d_in[5];
  const float* bias = (const float*)d_in[6];
  float* out = (float*)d_out;

  char* ws = (char*)d_ws;
  // ws layout (bytes): R 301,989,888 | xT 50,331,648 | BtCat 12,582,912 |
  //                    As 6,291,456 | adp 4,194,304   => total ~375.4 MB
  __hip_bfloat16* R = (__hip_bfloat16*)(ws + 0);
  __hip_bfloat16* xT = (__hip_bfloat16*)(ws + 301989888ull);
  __hip_bfloat16* BtCat = (__hip_bfloat16*)(ws + 352321536ull);
  __hip_bfloat16* As = (__hip_bfloat16*)(ws + 364904448ull);
  float* adp = (float*)(ws + 371195904ull);

  // 1. adaptive adjacency
  adp_kernel<<<dim3(1024), dim3(128), 0, stream>>>(nv1, nv2, adp);
  // 2. bf16 casts: straight (As) + transposed (BtCat slices 0,2,4)
  cast_transpose<<<dim3(16, 16, 3), dim3(256), 0, stream>>>(A1, A2, adp, As, BtCat);
  // 3. squares: BtCat slice 2z+1 = (a^2)^T = At @ As^T   (M=N=K=1024)
  gemm_bt<0><<<dim3(8, 8, 3), dim3(256), 0, stream>>>(
      BtCat, As, BtCat + 1048576ull, 1024, 1024, 1024,
      2097152ll, 1048576ll, 2097152ll);
  // 4. x -> xT bf16
  transpose_x_k<<<dim3(2048), dim3(256), 0, stream>>>(x, xT);
  // 5. main diffusion GEMM: R = xT @ BtCat^T  (M=24576, N=6144, K=1024)
  //    256x128 tile, 4 waves, 2 blocks/CU, counted-vmcnt ring pipeline
  gemm256<<<dim3(48, 96), dim3(256), 0, stream>>>(xT, BtCat, R);
  // 6. channel mix + bias -> out
  mix_kernel<<<dim3(16, 64), dim3(256), 0, stream>>>(R, xT, W, bias, out);
}